// Round 1
// baseline (701.882 us; speedup 1.0000x reference)
//
#include <hip/hip_runtime.h>
#include <math.h>

typedef unsigned long long u64;

#define T_LEN   4096
#define VOCAB   50257
#define TOP_M   4
#define WEIGHT  0.5f

// B = 1315423911; powers mod 2^64 computed at compile time (unsigned wrap is defined)
#define HASH_B  1315423911ull

// ---------------- Kernel 1: parallel fingerprint / slot / want_key ----------------
__global__ void precompute_kernel(const int* __restrict__ ids,
                                  int* __restrict__ slot,
                                  u64* __restrict__ wkey) {
    int t = blockIdx.x * blockDim.x + threadIdx.x;
    if (t >= T_LEN) return;
    const u64 B1 = HASH_B;
    const u64 B2 = B1 * B1;
    const u64 B3 = B2 * B1;
    if (t < 3) { slot[t] = -1; wkey[t] = 0ull; return; }
    u64 a = (u64)(unsigned)(ids[t - 3] + 1);
    u64 b = (u64)(unsigned)(ids[t - 2] + 1);
    u64 c = (u64)(unsigned)(ids[t - 1] + 1);
    u64 d = (u64)(unsigned)(ids[t]     + 1);
    u64 fp = a * B3 + b * B2 + c * B1 + d;   // wraps mod 2^64
    slot[t] = (int)(fp & 0xFFFFull);
    wkey[t] = fp + 1ull;
}

// ---------------- Kernel 2: per-slot chains, table state in registers ----------------
__global__ void __launch_bounds__(256) chain_kernel(const int* __restrict__ ids,
                                                    const int* __restrict__ slot_g,
                                                    const u64* __restrict__ wkey_g,
                                                    int* __restrict__ idxs,
                                                    float* __restrict__ vals) {
    __shared__ int s[T_LEN];
    int tid = threadIdx.x;
    for (int i = tid; i < T_LEN; i += blockDim.x) s[i] = slot_g[i];
    __syncthreads();

    int t = blockIdx.x * blockDim.x + tid;
    if (t >= T_LEN) return;
    int mys = s[t];
    if (mys < 0) {
        #pragma unroll
        for (int m = 0; m < TOP_M; ++m) { idxs[t * TOP_M + m] = 0; vals[t * TOP_M + m] = 0.0f; }
        return;
    }
    // chain head iff no earlier step maps to the same slot
    for (int tp = t - 1; tp >= 3; --tp)
        if (s[tp] == mys) return;

    // register-resident slot state
    u64 key = 0ull;
    int tk[TOP_M] = {0, 0, 0, 0};
    int cs[TOP_M] = {0, 0, 0, 0};

    for (int tp = t; tp < T_LEN; ++tp) {
        if (s[tp] != mys) continue;
        u64 wk = wkey_g[tp];
        bool key_match = (key == wk);

        int tot = 0;
        #pragma unroll
        for (int m = 0; m < TOP_M; ++m) tot += (tk[m] > 0) ? cs[m] : 0;
        bool emit = key_match && (tot > 0);
        float denom = fmaxf((float)tot, 1.0f);

        #pragma unroll
        for (int m = 0; m < TOP_M; ++m) {
            bool ok = emit && (tk[m] > 0) && (cs[m] > 0);
            float p = fmaxf(1e-9f, (float)cs[m] / denom);
            vals[tp * TOP_M + m] = ok ? (logf(p) * WEIGHT) : 0.0f;
            idxs[tp * TOP_M + m] = ok ? (tk[m] - 1) : 0;
        }

        if (tp < T_LEN - 1) {   // do_upd = active & has_next
            if (!key_match) {   // reset
                #pragma unroll
                for (int m = 0; m < TOP_M; ++m) { tk[m] = 0; cs[m] = 0; }
            }
            key = wk;
            int ntp1 = ids[tp + 1] + 1;

            // first index with tk==ntp1
            int ins = -1;
            #pragma unroll
            for (int m = 0; m < TOP_M; ++m) if (ins < 0 && tk[m] == ntp1) ins = m;
            bool matched = (ins >= 0);
            // else first empty
            if (ins < 0) {
                #pragma unroll
                for (int m = 0; m < TOP_M; ++m) if (ins < 0 && tk[m] == 0) ins = m;
            }
            // else first argmin count
            if (ins < 0) {
                int best = cs[0]; ins = 0;
                #pragma unroll
                for (int m = 1; m < TOP_M; ++m) if (cs[m] < best) { best = cs[m]; ins = m; }
            }
            int cur = 0;
            #pragma unroll
            for (int m = 0; m < TOP_M; ++m) if (m == ins) cur = cs[m];
            int new_cnt = matched ? min(65535, cur + 1) : 1;
            #pragma unroll
            for (int m = 0; m < TOP_M; ++m) if (m == ins) { tk[m] = ntp1; cs[m] = new_cnt; }
        }
    }
}

// ---------------- Kernel 3: dense copy logits -> out (float4) ----------------
__global__ void copy_kernel(const float4* __restrict__ src, float4* __restrict__ dst,
                            size_t n4, const float* __restrict__ src_s,
                            float* __restrict__ dst_s, size_t n_total) {
    size_t i = (size_t)blockIdx.x * blockDim.x + threadIdx.x;
    size_t stride = (size_t)gridDim.x * blockDim.x;
    for (size_t k = i; k < n4; k += stride) dst[k] = src[k];
    // scalar tail (n_total not divisible by 4) — handled by first few threads
    size_t tail = n_total - n4 * 4;
    if (i < tail) dst_s[n4 * 4 + i] = src_s[n4 * 4 + i];
}

// ---------------- Kernel 4: sparse scatter-add of deltas ----------------
__global__ void scatter_kernel(const int* __restrict__ idxs,
                               const float* __restrict__ vals,
                               float* __restrict__ out) {
    int i = blockIdx.x * blockDim.x + threadIdx.x;
    if (i >= T_LEN * TOP_M) return;
    float v = vals[i];
    if (v != 0.0f) {
        int t = i / TOP_M;
        atomicAdd(out + (size_t)t * VOCAB + idxs[i], v);
    }
}

extern "C" void kernel_launch(void* const* d_in, const int* in_sizes, int n_in,
                              void* d_out, int out_size, void* d_ws, size_t ws_size,
                              hipStream_t stream) {
    const float* logits = (const float*)d_in[0];
    const int*   ids    = (const int*)d_in[1];
    float*       out    = (float*)d_out;

    // workspace layout (all 16B-aligned offsets)
    char* ws = (char*)d_ws;
    int*  slot = (int*)(ws);                     // 4096 * 4  = 16 KB
    u64*  wkey = (u64*)(ws + 16384);             // 4096 * 8  = 32 KB
    int*  idxs = (int*)(ws + 16384 + 32768);     // 16384 * 4 = 64 KB
    float* vals = (float*)(ws + 16384 + 32768 + 65536); // 64 KB

    precompute_kernel<<<(T_LEN + 255) / 256, 256, 0, stream>>>(ids, slot, wkey);
    chain_kernel<<<(T_LEN + 255) / 256, 256, 0, stream>>>(ids, slot, wkey, idxs, vals);

    size_t n_total = (size_t)out_size;
    size_t n4 = n_total / 4;
    copy_kernel<<<2048, 256, 0, stream>>>((const float4*)logits, (float4*)out, n4,
                                          logits, out, n_total);
    scatter_kernel<<<(T_LEN * TOP_M + 255) / 256, 256, 0, stream>>>(idxs, vals, out);
}

// Round 2
// 473.617 us; speedup vs baseline: 1.4820x; 1.4820x over previous
//
#include <hip/hip_runtime.h>
#include <math.h>

typedef unsigned long long u64;

#define T_LEN   4096
#define VOCAB   50257
#define TOP_M   4
#define WEIGHT  0.5f
#define HASH_B  1315423911ull

#define CHAIN_BLOCKS  32
#define CHAIN_THREADS 128

// ---------------- Kernel 1: parallel fingerprint / slot / want_key ----------------
// fp_t = (id[t-3]+1)*B^3 + (id[t-2]+1)*B^2 + (id[t-1]+1)*B + (id[t]+1)  (mod 2^64)
__global__ void precompute_kernel(const int* __restrict__ ids,
                                  int* __restrict__ slot,
                                  u64* __restrict__ wkey) {
    int t = blockIdx.x * blockDim.x + threadIdx.x;
    if (t >= T_LEN) return;
    const u64 B1 = HASH_B;
    const u64 B2 = B1 * B1;
    const u64 B3 = B2 * B1;
    if (t < 3) { slot[t] = -1; wkey[t] = 0ull; return; }   // -1 sentinel: never matches
    u64 a = (u64)(unsigned)(ids[t - 3] + 1);
    u64 b = (u64)(unsigned)(ids[t - 2] + 1);
    u64 c = (u64)(unsigned)(ids[t - 1] + 1);
    u64 d = (u64)(unsigned)(ids[t]     + 1);
    u64 fp = a * B3 + b * B2 + c * B1 + d;                 // wraps mod 2^64
    slot[t] = (int)(fp & 0xFFFFull);
    wkey[t] = fp + 1ull;
}

// ---------------- Kernel 2: per-slot chains, table state in registers ----------------
// One thread per position t. Single forward pass over the slot array (batched,
// pipelined LDS reads): positions tp<t matching my slot => I'm not the chain
// head (dead). Positions tp>=t matching => process (emit + table update) if head.
__global__ void __launch_bounds__(CHAIN_THREADS) chain_kernel(const int* __restrict__ ids,
                                                              const int* __restrict__ slot_g,
                                                              const u64* __restrict__ wkey_g,
                                                              int* __restrict__ idxs,
                                                              float* __restrict__ vals) {
    __shared__ int s[T_LEN];
    {
        int4* sw = (int4*)s;
        const int4* g4 = (const int4*)slot_g;
        for (int i = threadIdx.x; i < T_LEN / 4; i += CHAIN_THREADS) sw[i] = g4[i];
    }
    __syncthreads();

    int t = blockIdx.x * CHAIN_THREADS + threadIdx.x;
    if (t < 3) {
        *(int4*)&idxs[t * 4]   = make_int4(0, 0, 0, 0);
        *(float4*)&vals[t * 4] = make_float4(0.f, 0.f, 0.f, 0.f);
        return;
    }
    const int mys = s[t];

    // register-resident slot state
    u64 key = 0ull;
    int tk[TOP_M] = {0, 0, 0, 0};
    int cs[TOP_M] = {0, 0, 0, 0};
    bool dead = false;

    const int4* s4 = (const int4*)s;
    for (int qb = 0; qb < T_LEN / 4; qb += 8) {
        int4 v[8];
        #pragma unroll
        for (int u = 0; u < 8; ++u) v[u] = s4[qb + u];     // 8 independent ds_read_b128
        bool any = false;
        #pragma unroll
        for (int u = 0; u < 8; ++u)
            any |= (v[u].x == mys) | (v[u].y == mys) | (v[u].z == mys) | (v[u].w == mys);
        if (!any) continue;

        #pragma unroll
        for (int u = 0; u < 8; ++u) {
            #pragma unroll
            for (int j = 0; j < 4; ++j) {
                int sv = (j == 0) ? v[u].x : (j == 1) ? v[u].y : (j == 2) ? v[u].z : v[u].w;
                if (sv != mys) continue;
                int tp = (qb + u) * 4 + j;
                if (tp < t) { dead = true; continue; }
                if (dead) continue;

                // ---- process chain member at position tp ----
                u64 wk = wkey_g[tp];
                bool key_match = (key == wk);

                int tot = 0;
                #pragma unroll
                for (int m = 0; m < TOP_M; ++m) tot += (tk[m] > 0) ? cs[m] : 0;
                bool emit = key_match && (tot > 0);
                float denom = fmaxf((float)tot, 1.0f);

                int   oi[TOP_M];
                float ov[TOP_M];
                #pragma unroll
                for (int m = 0; m < TOP_M; ++m) {
                    bool ok = emit && (tk[m] > 0) && (cs[m] > 0);
                    float p = fmaxf(1e-9f, (float)cs[m] / denom);
                    ov[m] = ok ? (logf(p) * WEIGHT) : 0.0f;
                    oi[m] = ok ? (tk[m] - 1) : 0;
                }
                *(int4*)&idxs[tp * 4]   = make_int4(oi[0], oi[1], oi[2], oi[3]);
                *(float4*)&vals[tp * 4] = make_float4(ov[0], ov[1], ov[2], ov[3]);

                if (tp < T_LEN - 1) {                      // do_upd = active & has_next
                    if (!key_match) {
                        #pragma unroll
                        for (int m = 0; m < TOP_M; ++m) { tk[m] = 0; cs[m] = 0; }
                    }
                    key = wk;
                    int ntp1 = ids[tp + 1] + 1;

                    int ins = -1;
                    #pragma unroll
                    for (int m = 0; m < TOP_M; ++m) if (ins < 0 && tk[m] == ntp1) ins = m;
                    bool matched = (ins >= 0);
                    if (ins < 0) {
                        #pragma unroll
                        for (int m = 0; m < TOP_M; ++m) if (ins < 0 && tk[m] == 0) ins = m;
                    }
                    if (ins < 0) {
                        int best = cs[0]; ins = 0;
                        #pragma unroll
                        for (int m = 1; m < TOP_M; ++m) if (cs[m] < best) { best = cs[m]; ins = m; }
                    }
                    int cur = 0;
                    #pragma unroll
                    for (int m = 0; m < TOP_M; ++m) if (m == ins) cur = cs[m];
                    int new_cnt = matched ? min(65535, cur + 1) : 1;
                    #pragma unroll
                    for (int m = 0; m < TOP_M; ++m) if (m == ins) { tk[m] = ntp1; cs[m] = new_cnt; }
                }
            }
        }
        if (dead) break;   // not a head: everything after my first earlier twin is irrelevant
    }
}

// ---------------- Kernel 3: dense copy logits -> out (float4 grid-stride) ----------------
__global__ void copy_kernel(const float4* __restrict__ src, float4* __restrict__ dst,
                            size_t n4, const float* __restrict__ src_s,
                            float* __restrict__ dst_s, size_t n_total) {
    size_t i = (size_t)blockIdx.x * blockDim.x + threadIdx.x;
    size_t stride = (size_t)gridDim.x * blockDim.x;
    #pragma unroll 4
    for (size_t k = i; k < n4; k += stride) dst[k] = src[k];
    size_t tail = n_total - n4 * 4;
    if (i < tail) dst_s[n4 * 4 + i] = src_s[n4 * 4 + i];
}

// ---------------- Kernel 4: sparse scatter-add of deltas ----------------
__global__ void scatter_kernel(const int* __restrict__ idxs,
                               const float* __restrict__ vals,
                               float* __restrict__ out) {
    int i = blockIdx.x * blockDim.x + threadIdx.x;
    if (i >= T_LEN * TOP_M) return;
    float v = vals[i];
    if (v != 0.0f) {
        int t = i / TOP_M;
        atomicAdd(out + (size_t)t * VOCAB + idxs[i], v);
    }
}

extern "C" void kernel_launch(void* const* d_in, const int* in_sizes, int n_in,
                              void* d_out, int out_size, void* d_ws, size_t ws_size,
                              hipStream_t stream) {
    const float* logits = (const float*)d_in[0];
    const int*   ids    = (const int*)d_in[1];
    float*       out    = (float*)d_out;

    // workspace layout (16B-aligned offsets)
    char* ws = (char*)d_ws;
    int*   slot = (int*)(ws);                              // 4096*4  = 16 KB
    u64*   wkey = (u64*)(ws + 16384);                      // 4096*8  = 32 KB
    int*   idxs = (int*)(ws + 16384 + 32768);              // 16384*4 = 64 KB
    float* vals = (float*)(ws + 16384 + 32768 + 65536);    // 64 KB

    precompute_kernel<<<(T_LEN + 255) / 256, 256, 0, stream>>>(ids, slot, wkey);
    chain_kernel<<<CHAIN_BLOCKS, CHAIN_THREADS, 0, stream>>>(ids, slot, wkey, idxs, vals);

    size_t n_total = (size_t)out_size;
    size_t n4 = n_total / 4;
    copy_kernel<<<2048, 256, 0, stream>>>((const float4*)logits, (float4*)out, n4,
                                          logits, out, n_total);
    scatter_kernel<<<(T_LEN * TOP_M + 255) / 256, 256, 0, stream>>>(idxs, vals, out);
}

// Round 4
// 364.189 us; speedup vs baseline: 1.9272x; 1.3005x over previous
//
#include <hip/hip_runtime.h>
#include <math.h>

typedef unsigned long long u64;
typedef float  f32x4 __attribute__((ext_vector_type(4)));
typedef int    i32x4 __attribute__((ext_vector_type(4)));

#define T_LEN   4096
#define VOCAB   50257
#define TOP_M   4
#define WEIGHT  0.5f
#define HASH_B  1315423911ull

#define CHAIN_BLOCKS  32
#define CHAIN_THREADS 128

// ---------------- Kernel 1: per-slot chains, everything staged in LDS ----------------
// Stages ids into LDS, computes slot[t] in LDS, then one thread per position t:
// single forward pass over the slot array (wave-uniform broadcast LDS reads).
// Positions tp<t matching my slot => I'm not the chain head (dead).
// Positions tp>=t matching => process (emit + table update) if head.
// wkey(tp) recomputed in-register from LDS ids (cheap: 3 mul-adds).
__global__ void __launch_bounds__(CHAIN_THREADS) chain_kernel(const int* __restrict__ ids,
                                                              int* __restrict__ idxs,
                                                              float* __restrict__ vals) {
    __shared__ int sids[T_LEN];
    __shared__ int s[T_LEN];
    {
        i32x4* dst4 = (i32x4*)sids;
        const i32x4* g4 = (const i32x4*)ids;
        for (int i = threadIdx.x; i < T_LEN / 4; i += CHAIN_THREADS) dst4[i] = g4[i];
    }
    __syncthreads();
    const u64 B1 = HASH_B;
    const u64 B2 = B1 * B1;
    const u64 B3 = B2 * B1;
    for (int i = threadIdx.x; i < T_LEN; i += CHAIN_THREADS) {
        if (i < 3) { s[i] = -1; continue; }
        u64 fp = (u64)(unsigned)(sids[i - 3] + 1) * B3
               + (u64)(unsigned)(sids[i - 2] + 1) * B2
               + (u64)(unsigned)(sids[i - 1] + 1) * B1
               + (u64)(unsigned)(sids[i]     + 1);
        s[i] = (int)(fp & 0xFFFFull);
    }
    __syncthreads();

    int t = blockIdx.x * CHAIN_THREADS + threadIdx.x;
    if (t < 3) {
        *(i32x4*)&idxs[t * 4]  = (i32x4){0, 0, 0, 0};
        *(f32x4*)&vals[t * 4]  = (f32x4){0.f, 0.f, 0.f, 0.f};
        return;
    }
    const int mys = s[t];

    // register-resident slot state
    u64 key = 0ull;
    int tk[TOP_M] = {0, 0, 0, 0};
    int cs[TOP_M] = {0, 0, 0, 0};
    bool dead = false;

    const i32x4* s4 = (const i32x4*)s;
    for (int qb = 0; qb < T_LEN / 4; qb += 8) {
        i32x4 v[8];
        #pragma unroll
        for (int u = 0; u < 8; ++u) v[u] = s4[qb + u];     // broadcast ds_read_b128 ×8
        bool any = false;
        #pragma unroll
        for (int u = 0; u < 8; ++u)
            any |= (v[u].x == mys) | (v[u].y == mys) | (v[u].z == mys) | (v[u].w == mys);
        if (!any) continue;

        #pragma unroll
        for (int u = 0; u < 8; ++u) {
            #pragma unroll
            for (int j = 0; j < 4; ++j) {
                int sv = (j == 0) ? v[u].x : (j == 1) ? v[u].y : (j == 2) ? v[u].z : v[u].w;
                if (sv != mys) continue;
                int tp = (qb + u) * 4 + j;
                if (tp < t) { dead = true; continue; }
                if (dead) continue;

                // ---- process chain member at position tp ----
                u64 wk = (u64)(unsigned)(sids[tp - 3] + 1) * B3
                       + (u64)(unsigned)(sids[tp - 2] + 1) * B2
                       + (u64)(unsigned)(sids[tp - 1] + 1) * B1
                       + (u64)(unsigned)(sids[tp]     + 1) + 1ull;
                bool key_match = (key == wk);

                int tot = 0;
                #pragma unroll
                for (int m = 0; m < TOP_M; ++m) tot += (tk[m] > 0) ? cs[m] : 0;
                bool emit = key_match && (tot > 0);
                float denom = fmaxf((float)tot, 1.0f);

                int   oi[TOP_M];
                float ov[TOP_M];
                #pragma unroll
                for (int m = 0; m < TOP_M; ++m) {
                    bool ok = emit && (tk[m] > 0) && (cs[m] > 0);
                    float p = fmaxf(1e-9f, (float)cs[m] / denom);
                    ov[m] = ok ? (logf(p) * WEIGHT) : 0.0f;
                    oi[m] = ok ? (tk[m] - 1) : 0;
                }
                *(i32x4*)&idxs[tp * 4] = (i32x4){oi[0], oi[1], oi[2], oi[3]};
                *(f32x4*)&vals[tp * 4] = (f32x4){ov[0], ov[1], ov[2], ov[3]};

                if (tp < T_LEN - 1) {                      // do_upd = active & has_next
                    if (!key_match) {
                        #pragma unroll
                        for (int m = 0; m < TOP_M; ++m) { tk[m] = 0; cs[m] = 0; }
                    }
                    key = wk;
                    int ntp1 = sids[tp + 1] + 1;

                    int ins = -1;
                    #pragma unroll
                    for (int m = 0; m < TOP_M; ++m) if (ins < 0 && tk[m] == ntp1) ins = m;
                    bool matched = (ins >= 0);
                    if (ins < 0) {
                        #pragma unroll
                        for (int m = 0; m < TOP_M; ++m) if (ins < 0 && tk[m] == 0) ins = m;
                    }
                    if (ins < 0) {
                        int best = cs[0]; ins = 0;
                        #pragma unroll
                        for (int m = 1; m < TOP_M; ++m) if (cs[m] < best) { best = cs[m]; ins = m; }
                    }
                    int cur = 0;
                    #pragma unroll
                    for (int m = 0; m < TOP_M; ++m) if (m == ins) cur = cs[m];
                    int new_cnt = matched ? min(65535, cur + 1) : 1;
                    #pragma unroll
                    for (int m = 0; m < TOP_M; ++m) if (m == ins) { tk[m] = ntp1; cs[m] = new_cnt; }
                }
            }
        }
        if (dead) break;   // not a head: everything after my first earlier twin is irrelevant
    }
}

// ---------------- Kernel 2: dense copy logits -> out (flat, one float4/thread, nt) ----------------
__global__ void copy_kernel(const f32x4* __restrict__ src, f32x4* __restrict__ dst,
                            size_t n4) {
    size_t k = (size_t)blockIdx.x * blockDim.x + threadIdx.x;
    if (k < n4) {
        f32x4 v = __builtin_nontemporal_load(&src[k]);
        __builtin_nontemporal_store(v, &dst[k]);
    }
}

// scalar tail (out_size % 4), launched only if needed
__global__ void copy_tail_kernel(const float* __restrict__ src, float* __restrict__ dst,
                                 size_t start, size_t n_total) {
    size_t k = start + threadIdx.x;
    if (k < n_total) dst[k] = src[k];
}

// ---------------- Kernel 3: sparse scatter-add of deltas ----------------
__global__ void scatter_kernel(const int* __restrict__ idxs,
                               const float* __restrict__ vals,
                               float* __restrict__ out) {
    int i = blockIdx.x * blockDim.x + threadIdx.x;
    if (i >= T_LEN * TOP_M) return;
    float v = vals[i];
    if (v != 0.0f) {
        int t = i / TOP_M;
        atomicAdd(out + (size_t)t * VOCAB + idxs[i], v);
    }
}

extern "C" void kernel_launch(void* const* d_in, const int* in_sizes, int n_in,
                              void* d_out, int out_size, void* d_ws, size_t ws_size,
                              hipStream_t stream) {
    const float* logits = (const float*)d_in[0];
    const int*   ids    = (const int*)d_in[1];
    float*       out    = (float*)d_out;

    // workspace layout (16B-aligned offsets)
    char* ws = (char*)d_ws;
    int*   idxs = (int*)(ws);              // 16384*4 = 64 KB
    float* vals = (float*)(ws + 65536);    // 64 KB

    chain_kernel<<<CHAIN_BLOCKS, CHAIN_THREADS, 0, stream>>>(ids, idxs, vals);

    size_t n_total = (size_t)out_size;
    size_t n4 = n_total / 4;
    size_t nblk = (n4 + 255) / 256;
    copy_kernel<<<(uint32_t)nblk, 256, 0, stream>>>((const f32x4*)logits, (f32x4*)out, n4);
    if (n_total - n4 * 4)
        copy_tail_kernel<<<1, 64, 0, stream>>>(logits, out, n4 * 4, n_total);

    scatter_kernel<<<(T_LEN * TOP_M + 255) / 256, 256, 0, stream>>>(idxs, vals, out);
}